// Round 14
// baseline (3026.399 us; speedup 1.0000x reference)
//
#include <hip/hip_runtime.h>

typedef _Float16 half_t;
typedef _Float16 half2_t __attribute__((ext_vector_type(2)));
typedef _Float16 half8_t __attribute__((ext_vector_type(8)));
typedef float floatx4 __attribute__((ext_vector_type(4)));
typedef unsigned int u32;

#define EMBED 512
#define HID 512
#define BATCH 32
#define SEQ 1024
#define M_TOT (BATCH * SEQ)          // 32768

static __device__ __forceinline__ float tanh_fast(float x) {
  float e = __expf(2.0f * x);
  return 1.0f - 2.0f * __builtin_amdgcn_rcpf(e + 1.0f);
}
static __device__ __forceinline__ half8_t bc8(uint4 v) {
  return __builtin_bit_cast(half8_t, v);
}
static __device__ __forceinline__ half2_t bch2(u32 v) {
  return __builtin_bit_cast(half2_t, v);
}

// ---------------- K0: weight conversion / layout prep ----------------
// whh_m: W_hh in MFMA B-fragment layout (identical fragment mapping to k1's
// end-to-end validated B loads): frag (d, w, jt, kt), lane holds
// W[j = w*64+jt*16+(lane&15)][i = kt*32+(lane>>4)*8 + 0..7] as 4 u32.
// flat u32 idx = (((d*8+w)*4+jt)*16+kt)*256 + lane*4 + q
__global__ __launch_bounds__(256) void k0_prep(
    const float* __restrict__ Wihf, const float* __restrict__ Whhf,
    const float* __restrict__ bihf, const float* __restrict__ bhhf,
    const float* __restrict__ Wihb, const float* __restrict__ Whhb,
    const float* __restrict__ bihb, const float* __restrict__ bhhb,
    half_t* __restrict__ wih16, u32* __restrict__ whh_m,
    float* __restrict__ biassum) {
  const int g = blockIdx.x * 256 + threadIdx.x;  // grid 2048*256 = 524288
  {
    const int n = g >> 9, k = g & 511;
    const float* src = (n < 512) ? Wihf : Wihb;
    wih16[g] = (half_t)src[(size_t)(n & 511) * 512 + k];
  }
  if (g < 262144) {
    const int d = g >> 17;
    const int j = (g >> 8) & 511;
    const int p = g & 255;
    const int i = p << 1;
    const int w = j >> 6, jt = (j >> 4) & 3, jl = j & 15;
    const int kt = p >> 4;
    const int ko = (p & 15) >> 2, q = p & 3;
    const int lane = (ko << 4) + jl;
    const float* W = d ? Whhb : Whhf;
    half2_t h2 = {(half_t)W[(size_t)j * 512 + i], (half_t)W[(size_t)j * 512 + i + 1]};
    whh_m[((((((d << 3) + w) << 2) + jt) * 16 + kt) << 8) + (lane << 2) + q] =
        __builtin_bit_cast(u32, h2);
  }
  if (g < 1024) {
    biassum[g] = (g < 512) ? (bihf[g] + bhhf[g]) : (bihb[g - 512] + bhhb[g - 512]);
  }
}

// ---------------- K1: input projection (MFMA f16) ----------------
// Writes x in k2's D-fragment order:
// block (d*2+grp, s) of 8192 f16; idx = ((w2*4+jt2)*64 + lf)*4 + qf
// where lf = ((m>>2)<<4)|(j&15), qf = m&3, m = batch&15, grp = batch>>4.
__global__ __launch_bounds__(256) void k1_proj(
    const int* __restrict__ tok, const float* __restrict__ emb,
    const half_t* __restrict__ wih, const float* __restrict__ biassum,
    half_t* __restrict__ x) {
  __shared__ half_t At[64][520];
  const int t = threadIdx.x;
  const int m0 = blockIdx.x * 64;
  {
    const int r = t >> 2;
    const int c0 = (t & 3) << 7;
    const int token = tok[m0 + r];
    const float* er = emb + (size_t)token * EMBED + c0;
#pragma unroll
    for (int cc = 0; cc < 128; cc += 4) {
      floatx4 v = *(const floatx4*)(er + cc);
      At[r][c0 + cc]     = (half_t)v[0];
      At[r][c0 + cc + 1] = (half_t)v[1];
      At[r][c0 + cc + 2] = (half_t)v[2];
      At[r][c0 + cc + 3] = (half_t)v[3];
    }
  }
  __syncthreads();
  const int w = t >> 6, l = t & 63;
  const int lrow = l & 15, lk = (l >> 4) << 3;
  const int bb = m0 >> 10;            // batch (fixed per block: 64 | 1024)
  const int grp = (bb >> 4) & 1;
  const int mm = bb & 15;
  const int qf = mm & 3;
  const int lfm = (mm >> 2) << 4;
  const int s00 = (m0 & 1023) + ((l >> 4) << 2);
#pragma unroll 1
  for (int nb = 0; nb < 1024; nb += 256) {
    const int n0 = nb + w * 64;
    floatx4 acc[4][4] = {};
    for (int k0 = 0; k0 < 512; k0 += 32) {
      half8_t a[4], bf[4];
#pragma unroll
      for (int mi = 0; mi < 4; ++mi)
        a[mi] = *(const half8_t*)&At[mi * 16 + lrow][k0 + lk];
#pragma unroll
      for (int ni = 0; ni < 4; ++ni)
        bf[ni] = *(const half8_t*)(wih + (size_t)(n0 + ni * 16 + lrow) * 512 + k0 + lk);
#pragma unroll
      for (int mi = 0; mi < 4; ++mi)
#pragma unroll
        for (int ni = 0; ni < 4; ++ni)
          acc[mi][ni] = __builtin_amdgcn_mfma_f32_16x16x32_f16(a[mi], bf[ni], acc[mi][ni], 0, 0, 0);
    }
#pragma unroll
    for (int ni = 0; ni < 4; ++ni) {
      const int n = n0 + ni * 16 + lrow;
      const float bias = biassum[n];
      const int dd = n >> 9, j = n & 511;
      const int w2 = j >> 6, jt2 = (j >> 4) & 3;
      const int lf = lfm | (j & 15);
      half_t* base = x + (size_t)(dd * 2 + grp) * 1024 * 8192
                   + ((w2 * 4 + jt2) * 64 + lf) * 4 + qf;
#pragma unroll
      for (int mi = 0; mi < 4; ++mi) {
        const int sb = s00 + mi * 16;
#pragma unroll
        for (int q = 0; q < 4; ++q)
          base[(size_t)(sb + q) * 8192] = (half_t)(acc[mi][ni][q] + bias);
      }
    }
  }
}

// ---------------- K2: persistent RNN scan, 1 WG per (dir, 16-seq group) ----------------
// 4 WGs x 512 thr (8 waves). Wave w owns j in [w*64,+64) (4 j-tiles).
// Per step: D[16 m][64 j] = sum_k h[m][k] * W[j][k] via 64 MFMA 16x16x32.
// B-frags kt 0..11 in 48 named half8_t (MFMA-only uses -> AGPR-eligible);
// kt 12..15 in LDS (128 KB). h[16][512] f16 in LDS, XOR-swizzled.
// x pre-arranged in D-frag order (acc init); h written back to same block.
__global__ __launch_bounds__(512) void k2_scan(
    const u32* __restrict__ whh, half_t* __restrict__ xfrag) {
  __shared__ uint4 wlds4[8192];   // 128 KB: B-frags kt 12..15
  __shared__ u32 hls[4096];       // 16 KB: h[16][512] f16, swizzled
  const int t = threadIdx.x;
  const int w = t >> 6, l = t & 63;
  const int d = blockIdx.x >> 1, grp = blockIdx.x & 1;

  const uint4* wgt = (const uint4*)whh + (size_t)(d * 8 + w) * 4096 + l;
#define LB(JT, KT) const half8_t B_##JT##_##KT = bc8(wgt[(JT) * 1024 + (KT) * 64]);
#define LBROW(JT)                                                              \
  LB(JT, 0) LB(JT, 1) LB(JT, 2) LB(JT, 3) LB(JT, 4) LB(JT, 5)                  \
  LB(JT, 6) LB(JT, 7) LB(JT, 8) LB(JT, 9) LB(JT, 10) LB(JT, 11)
  LBROW(0) LBROW(1) LBROW(2) LBROW(3)

#pragma unroll
  for (int jt = 0; jt < 4; ++jt)
#pragma unroll
    for (int km = 0; km < 4; ++km)
      wlds4[((w * 4 + jt) * 4 + km) * 64 + l] = wgt[jt * 1024 + (12 + km) * 64];
#pragma unroll
  for (int r = 0; r < 8; ++r) hls[t + r * 512] = 0u;

  const int sdir = d ? -1 : 1;
  int s = d ? (SEQ - 1) : 0;
  half_t* xbase = xfrag + (size_t)(d * 2 + grp) * 1024 * 8192;
  const int xoff0 = ((w * 4) * 64 + l) * 4;   // +256 per jt
  uint2 xn0 = *(const uint2*)(xbase + (size_t)s * 8192 + xoff0);
  uint2 xn1 = *(const uint2*)(xbase + (size_t)s * 8192 + xoff0 + 256);
  uint2 xn2 = *(const uint2*)(xbase + (size_t)s * 8192 + xoff0 + 512);
  uint2 xn3 = *(const uint2*)(xbase + (size_t)s * 8192 + xoff0 + 768);

  char* hbase = (char*)hls + (l & 15) * 1024;   // A-read base (row = l&15)
  const int aswz = (l & 7) << 4;
  const int akoff = (l >> 4) * 16;
  char* hwb = (char*)hls;
  __syncthreads();

  for (int i = 0; i < SEQ; ++i) {
    uint2 xc0 = xn0, xc1 = xn1, xc2 = xn2, xc3 = xn3;
    const int sn = s + sdir;
    if (i < SEQ - 1) {
      const half_t* xs = xbase + (size_t)sn * 8192 + xoff0;
      xn0 = *(const uint2*)(xs);
      xn1 = *(const uint2*)(xs + 256);
      xn2 = *(const uint2*)(xs + 512);
      xn3 = *(const uint2*)(xs + 768);
    }
    floatx4 acc0, acc1, acc2, acc3;
    {
      half2_t pa, pb;
      pa = bch2(xc0.x); pb = bch2(xc0.y);
      acc0[0] = pa[0]; acc0[1] = pa[1]; acc0[2] = pb[0]; acc0[3] = pb[1];
      pa = bch2(xc1.x); pb = bch2(xc1.y);
      acc1[0] = pa[0]; acc1[1] = pa[1]; acc1[2] = pb[0]; acc1[3] = pb[1];
      pa = bch2(xc2.x); pb = bch2(xc2.y);
      acc2[0] = pa[0]; acc2[1] = pa[1]; acc2[2] = pb[0]; acc2[3] = pb[1];
      pa = bch2(xc3.x); pb = bch2(xc3.y);
      acc3[0] = pa[0]; acc3[1] = pa[1]; acc3[2] = pb[0]; acc3[3] = pb[1];
    }

#define KTSTEP(KT)                                                             \
  {                                                                            \
    half8_t a8 = bc8(*(const uint4*)(hbase + (((KT) * 64 + akoff) ^ aswz)));   \
    acc0 = __builtin_amdgcn_mfma_f32_16x16x32_f16(a8, B_0_##KT, acc0, 0, 0, 0);\
    acc1 = __builtin_amdgcn_mfma_f32_16x16x32_f16(a8, B_1_##KT, acc1, 0, 0, 0);\
    acc2 = __builtin_amdgcn_mfma_f32_16x16x32_f16(a8, B_2_##KT, acc2, 0, 0, 0);\
    acc3 = __builtin_amdgcn_mfma_f32_16x16x32_f16(a8, B_3_##KT, acc3, 0, 0, 0);\
  }
    KTSTEP(0) KTSTEP(1) KTSTEP(2) KTSTEP(3)
    KTSTEP(4) KTSTEP(5) KTSTEP(6) KTSTEP(7)
    KTSTEP(8) KTSTEP(9) KTSTEP(10) KTSTEP(11)

#define KTL(KM)                                                                \
  {                                                                            \
    half8_t a8 = bc8(*(const uint4*)(hbase + ((((12 + (KM)) * 64) + akoff) ^ aswz))); \
    acc0 = __builtin_amdgcn_mfma_f32_16x16x32_f16(                             \
        a8, bc8(wlds4[((w * 4 + 0) * 4 + (KM)) * 64 + l]), acc0, 0, 0, 0);     \
    acc1 = __builtin_amdgcn_mfma_f32_16x16x32_f16(                             \
        a8, bc8(wlds4[((w * 4 + 1) * 4 + (KM)) * 64 + l]), acc1, 0, 0, 0);     \
    acc2 = __builtin_amdgcn_mfma_f32_16x16x32_f16(                             \
        a8, bc8(wlds4[((w * 4 + 2) * 4 + (KM)) * 64 + l]), acc2, 0, 0, 0);     \
    acc3 = __builtin_amdgcn_mfma_f32_16x16x32_f16(                             \
        a8, bc8(wlds4[((w * 4 + 3) * 4 + (KM)) * 64 + l]), acc3, 0, 0, 0);     \
  }
    KTL(0) KTL(1) KTL(2) KTL(3)

    __syncthreads();   // all hls reads (A-frags) complete

    half_t* gout = xbase + (size_t)s * 8192 + xoff0;
#define EPI(JT, ACC)                                                           \
  {                                                                            \
    half_t h0 = (half_t)tanh_fast(ACC[0]);                                     \
    half_t h1 = (half_t)tanh_fast(ACC[1]);                                     \
    half_t h2 = (half_t)tanh_fast(ACC[2]);                                     \
    half_t h3 = (half_t)tanh_fast(ACC[3]);                                     \
    const int jj2 = (w * 64 + (JT) * 16 + (l & 15)) * 2;                       \
    const int mb = (l >> 4) << 2;                                              \
    *(half_t*)(hwb + (mb + 0) * 1024 + (jj2 ^ (((mb + 0) & 7) << 4))) = h0;    \
    *(half_t*)(hwb + (mb + 1) * 1024 + (jj2 ^ (((mb + 1) & 7) << 4))) = h1;    \
    *(half_t*)(hwb + (mb + 2) * 1024 + (jj2 ^ (((mb + 2) & 7) << 4))) = h2;    \
    *(half_t*)(hwb + (mb + 3) * 1024 + (jj2 ^ (((mb + 3) & 7) << 4))) = h3;    \
    half2_t lo = {h0, h1}, hi = {h2, h3};                                      \
    uint2 st;                                                                  \
    st.x = __builtin_bit_cast(u32, lo);                                        \
    st.y = __builtin_bit_cast(u32, hi);                                        \
    *(uint2*)(gout + (JT) * 256) = st;                                         \
  }
    EPI(0, acc0) EPI(1, acc1) EPI(2, acc2) EPI(3, acc3)

    s = sn;
    __syncthreads();   // hls (next h) ready
  }
#undef LB
#undef LBROW
#undef KTSTEP
#undef KTL
#undef EPI
}

// ---------------- K3: classifier (frag-layout decode) ----------------
// wave per (grp, s): reads fwd+bwd frag blocks (2 x 16 KB) coalesced,
// decodes (m, j) per element, reduces over j via shfl within 16-lane groups.
__global__ __launch_bounds__(256) void k3_cls(
    const half_t* __restrict__ xfrag, const float* __restrict__ wcls,
    const float* __restrict__ bcls, float* __restrict__ out) {
  __shared__ float wl[2048];
  for (int i = threadIdx.x; i < 2048; i += 256) wl[i] = wcls[i];
  __syncthreads();
  const int l = threadIdx.x & 63;
  const int wid = (blockIdx.x * 256 + threadIdx.x) >> 6;  // 0..2047
  const int grp = wid & 1, s = wid >> 1;
  float a00 = 0.f, a01 = 0.f, a10 = 0.f, a11 = 0.f;
  float a20 = 0.f, a21 = 0.f, a30 = 0.f, a31 = 0.f;
#pragma unroll
  for (int dd = 0; dd < 2; ++dd) {
    const half_t* blk = xfrag + (size_t)(dd * 2 + grp) * 1024 * 8192 + (size_t)s * 8192;
#pragma unroll
    for (int it = 0; it < 32; ++it) {
      uint2 v = *(const uint2*)(blk + it * 256 + l * 4);
      half2_t pa = bch2(v.x), pb = bch2(v.y);
      const int j = (it >> 2) * 64 + (it & 3) * 16 + (l & 15);
      const float w0 = wl[dd * 512 + j];
      const float w1 = wl[1024 + dd * 512 + j];
      a00 += (float)pa[0] * w0; a01 += (float)pa[0] * w1;
      a10 += (float)pa[1] * w0; a11 += (float)pa[1] * w1;
      a20 += (float)pb[0] * w0; a21 += (float)pb[0] * w1;
      a30 += (float)pb[1] * w0; a31 += (float)pb[1] * w1;
    }
  }
#pragma unroll
  for (int off = 1; off < 16; off <<= 1) {
    a00 += __shfl_xor(a00, off, 64); a01 += __shfl_xor(a01, off, 64);
    a10 += __shfl_xor(a10, off, 64); a11 += __shfl_xor(a11, off, 64);
    a20 += __shfl_xor(a20, off, 64); a21 += __shfl_xor(a21, off, 64);
    a30 += __shfl_xor(a30, off, 64); a31 += __shfl_xor(a31, off, 64);
  }
  if ((l & 15) == 0) {
    const int mq = l >> 4;
    const float b0 = bcls[0], b1 = bcls[1];
    const size_t ob = ((size_t)(grp * 16 + mq * 4) * 1024 + s) * 2;
    out[ob + 0 * 2048 + 0] = a00 + b0; out[ob + 0 * 2048 + 1] = a01 + b1;
    out[ob + 1 * 2048 + 0] = a10 + b0; out[ob + 1 * 2048 + 1] = a11 + b1;
    out[ob + 2 * 2048 + 0] = a20 + b0; out[ob + 2 * 2048 + 1] = a21 + b1;
    out[ob + 3 * 2048 + 0] = a30 + b0; out[ob + 3 * 2048 + 1] = a31 + b1;
  }
}

extern "C" void kernel_launch(void* const* d_in, const int* in_sizes, int n_in,
                              void* d_out, int out_size, void* d_ws, size_t ws_size,
                              hipStream_t stream) {
  const int*   tok  = (const int*)d_in[0];
  const float* emb  = (const float*)d_in[1];
  const float* Wihf = (const float*)d_in[2];
  const float* Whhf = (const float*)d_in[3];
  const float* bihf = (const float*)d_in[4];
  const float* bhhf = (const float*)d_in[5];
  const float* Wihb = (const float*)d_in[6];
  const float* Whhb = (const float*)d_in[7];
  const float* bihb = (const float*)d_in[8];
  const float* bhhb = (const float*)d_in[9];
  const float* Wcls = (const float*)d_in[10];
  const float* bcls = (const float*)d_in[11];
  float* out = (float*)d_out;

  char* ws = (char*)d_ws;
  u32*    whh_m   = (u32*)ws;                    // 1 MB (MFMA B-frag layout)
  half_t* wih16   = (half_t*)(ws + (1 << 20));   // 1 MB
  float*  biassum = (float*)(ws + (2 << 20));    // 4 KB
  half_t* xfrag   = (half_t*)(ws + (4 << 20));   // 64 MB (x-frags, overwritten by h-frags)

  hipLaunchKernelGGL(k0_prep, dim3(2048), dim3(256), 0, stream,
                     Wihf, Whhf, bihf, bhhf, Wihb, Whhb, bihb, bhhb,
                     wih16, whh_m, biassum);
  hipLaunchKernelGGL(k1_proj, dim3(512), dim3(256), 0, stream,
                     tok, emb, wih16, biassum, xfrag);
  hipLaunchKernelGGL(k2_scan, dim3(4), dim3(512), 0, stream, whh_m, xfrag);
  hipLaunchKernelGGL(k3_cls, dim3(512), dim3(256), 0, stream,
                     xfrag, Wcls, bcls, out);
}